// Round 21
// baseline (141.679 us; speedup 1.0000x reference)
//
#include <hip/hip_runtime.h>

#define N_NODES 50000
#define N_EDGES 600000
#define DIM 128
#define NCLS 10
#define ELLW 64                 // max degree (mean 12; P(>64) astronomically small)
#define CURSTRIDE 16            // one cursor per 64B line
#define EPSF 1e-15f
#define MAXNORM 0.99999f        // 1 - 1e-5
#define NTILE 782               // ceil(50000/64)
#define FILLB 586               // ceil(600000/(256*4))
#define XFB 512                 // persistent transform blocks (layer 1)
#define SPLIT 30784             // back-half pipeline split (= 481*64, mult of 8)
#define STILE 481               // SPLIT/64
#define GA_BLKS 3848            // SPLIT/8 (gather blocks, 8 nodes/block)
#define GB_BLKS 2402            // (N_NODES-SPLIT)/8

typedef __attribute__((ext_vector_type(8))) short bf16x8;
typedef __attribute__((ext_vector_type(4))) float f32x4;

__device__ inline float waveSum(float v) {
#pragma unroll
  for (int o = 1; o < 64; o <<= 1) v += __shfl_xor(v, o, 64);
  return v;
}

__device__ inline unsigned short f2bf(float f) {
  union { float f; unsigned u; } c; c.f = f;
  return (unsigned short)((c.u + 0x7FFFu + ((c.u >> 16) & 1u)) >> 16);
}
__device__ inline float bf_lo(unsigned u) {
  union { unsigned u; float f; } c; c.u = u << 16; return c.f;
}
__device__ inline float bf_hi(unsigned u) {
  union { unsigned u; float f; } c; c.u = u & 0xFFFF0000u; return c.f;
}

// ---------------- init: zero cursors + convert W1/W2 to bf16 ----------------
__global__ __launch_bounds__(256) void init_kernel(
    int* __restrict__ cursor, const float* __restrict__ W1, const float* __restrict__ W2,
    unsigned short* __restrict__ W1b, unsigned short* __restrict__ W2b)
{
  int i = blockIdx.x * 256 + threadIdx.x;
  if (i < N_NODES) cursor[i * CURSTRIDE] = 0;
  if (i < DIM * DIM) {
    W1b[i] = f2bf(W1[i]);
    W2b[i] = f2bf(W2[i]);
  }
}

// ---------------- fused: ELL fill + layer-1 transform (proven ~48us) -------------
__global__ __launch_bounds__(256, 2) void fill_transform(
    const int* __restrict__ src, const int* __restrict__ dst,
    int* __restrict__ cursor, unsigned short* __restrict__ ell,
    const float* __restrict__ x, const unsigned short* __restrict__ Wb,
    const float* __restrict__ b, unsigned short* __restrict__ y)
{
  __shared__ __align__(16) unsigned short At[64 * DIM];

  if (blockIdx.x < FILLB) {
    const int nthr = FILLB * 256;
    const int e = blockIdx.x * 256 + threadIdx.x;
    const int e0 = e, e1 = e + nthr, e2 = e + 2 * nthr, e3 = e + 3 * nthr;
    int d0, d1, d2, d3, s0, s1, s2, s3;
    if (e0 < N_EDGES) { d0 = dst[e0]; s0 = src[e0]; }
    if (e1 < N_EDGES) { d1 = dst[e1]; s1 = src[e1]; }
    if (e2 < N_EDGES) { d2 = dst[e2]; s2 = src[e2]; }
    if (e3 < N_EDGES) { d3 = dst[e3]; s3 = src[e3]; }
    int p0, p1, p2, p3;
    if (e0 < N_EDGES) p0 = atomicAdd(&cursor[d0 * CURSTRIDE], 1);
    if (e1 < N_EDGES) p1 = atomicAdd(&cursor[d1 * CURSTRIDE], 1);
    if (e2 < N_EDGES) p2 = atomicAdd(&cursor[d2 * CURSTRIDE], 1);
    if (e3 < N_EDGES) p3 = atomicAdd(&cursor[d3 * CURSTRIDE], 1);
    if (e0 < N_EDGES) ell[(size_t)d0 * ELLW + p0] = (unsigned short)s0;
    if (e1 < N_EDGES) ell[(size_t)d1 * ELLW + p1] = (unsigned short)s1;
    if (e2 < N_EDGES) ell[(size_t)d2 * ELLW + p2] = (unsigned short)s2;
    if (e3 < N_EDGES) ell[(size_t)d3 * ELLW + p3] = (unsigned short)s3;
    return;
  }

  // ---------------- transform path (layer 1: f32 manifold in) ----------------
  const int tid = threadIdx.x;
  const int w = tid >> 6;
  const int l = tid & 63;
  const int lr = l & 15;
  const int lg = l >> 4;

  bf16x8 bf[8][4];
#pragma unroll
  for (int n = 0; n < 8; ++n)
#pragma unroll
    for (int kc = 0; kc < 4; ++kc)
      bf[n][kc] = *(const bf16x8*)(Wb + (n * 16 + lr) * DIM + kc * 32 + lg * 8);

  float bias[8];
#pragma unroll
  for (int n = 0; n < 8; ++n) bias[n] = b[n * 16 + lr];

  const int row = w * 16 + lr;

  for (int tile = blockIdx.x - FILLB; tile < NTILE; tile += XFB) {
    const int base = tile * 64;
    const int node = base + row;
    __syncthreads();

    float v[32];
    if (node < N_NODES) {
      const float4* xr = (const float4*)(x + (size_t)node * DIM + lg * 32);
#pragma unroll
      for (int q = 0; q < 8; ++q) {
        float4 f = xr[q];
        v[q * 4 + 0] = f.x; v[q * 4 + 1] = f.y; v[q * 4 + 2] = f.z; v[q * 4 + 3] = f.w;
      }
    } else {
#pragma unroll
      for (int q = 0; q < 32; ++q) v[q] = 0.f;
    }
    float sq = 0.f;
#pragma unroll
    for (int q = 0; q < 32; ++q) sq += v[q] * v[q];
    sq += __shfl_xor(sq, 16, 64);
    sq += __shfl_xor(sq, 32, 64);
    float n1 = sqrtf(sq);
    float nc = fmaxf(n1, EPSF);
    float nm = fminf(nc, MAXNORM);
    float scale = 0.5f * logf((1.f + nm) / (1.f - nm)) / nc;
#pragma unroll
    for (int s = 0; s < 4; ++s) {
      unsigned short tmp[8];
#pragma unroll
      for (int e = 0; e < 8; ++e) tmp[e] = f2bf(v[s * 8 + e] * scale);
      int byte = row * 256 + lg * 64 + s * 16;
      byte ^= (row & 7) << 4;
      *(bf16x8*)((char*)At + byte) = *(const bf16x8*)tmp;
    }
    __syncthreads();

    f32x4 acc[8];
#pragma unroll
    for (int n = 0; n < 8; ++n) {
      acc[n][0] = bias[n]; acc[n][1] = bias[n]; acc[n][2] = bias[n]; acc[n][3] = bias[n];
    }
#pragma unroll
    for (int kc = 0; kc < 4; ++kc) {
      int byte = row * 256 + kc * 64 + lg * 16;
      byte ^= (row & 7) << 4;
      bf16x8 af = *(const bf16x8*)((const char*)At + byte);
#pragma unroll
      for (int n = 0; n < 8; ++n)
        acc[n] = __builtin_amdgcn_mfma_f32_16x16x32_bf16(af, bf[n][kc], acc[n], 0, 0, 0);
    }

    float rs[4];
#pragma unroll
    for (int j = 0; j < 4; ++j) {
      float s2 = 0.f;
#pragma unroll
      for (int n = 0; n < 8; ++n) s2 += acc[n][j] * acc[n][j];
      s2 += __shfl_xor(s2, 1, 64);
      s2 += __shfl_xor(s2, 2, 64);
      s2 += __shfl_xor(s2, 4, 64);
      s2 += __shfl_xor(s2, 8, 64);
      float n2 = sqrtf(s2);
      float n2c = fmaxf(n2, EPSF);
      rs[j] = tanhf(n2c) / n2c;
    }
#pragma unroll
    for (int j = 0; j < 4; ++j) {
      int nrow = base + w * 16 + lg * 4 + j;
      if (nrow < N_NODES) {
        unsigned short* yr = y + (size_t)nrow * DIM + lr;
#pragma unroll
        for (int n = 0; n < 8; ++n) yr[n * 16] = f2bf(acc[n][j] * rs[j]);
      }
    }
  }
}

// ---------------- gather role: 2 nodes/wave, 8 nodes/block, node range offset ----
__device__ __forceinline__ void do_gather2(
    const unsigned short* __restrict__ y, const int* __restrict__ cursor,
    const unsigned short* __restrict__ ell, unsigned short* __restrict__ tout,
    int blkid, int nodeLo)
{
  const int wave = (int)threadIdx.x >> 6;
  const int lane = threadIdx.x & 63;
  const int nodeA = nodeLo + blkid * 8 + wave * 2;
  const int nodeB = nodeA + 1;

  const int cntA = cursor[nodeA * CURSTRIDE];
  const int cntB = cursor[nodeB * CURSTRIDE];
  const int idxA = (int)ell[(size_t)nodeA * ELLW + lane];  // unconditional load
  const int idxB = (int)ell[(size_t)nodeB * ELLW + lane];

  float2 aA0 = {0.f, 0.f}, aA1 = {0.f, 0.f};
  float2 aB0 = {0.f, 0.f}, aB1 = {0.f, 0.f};

  unsigned uA[16], uB[16];
#pragma unroll
  for (int q = 0; q < 16; ++q) {
    int sA = __shfl(idxA, q, 64);
    int sB = __shfl(idxB, q, 64);
    uA[q] = ((const unsigned*)(y + (size_t)sA * DIM))[lane];
    uB[q] = ((const unsigned*)(y + (size_t)sB * DIM))[lane];
  }
#pragma unroll
  for (int q = 0; q < 16; ++q) {
    float vx = (q < cntA) ? bf_lo(uA[q]) : 0.f;
    float vy = (q < cntA) ? bf_hi(uA[q]) : 0.f;
    float wx = (q < cntB) ? bf_lo(uB[q]) : 0.f;
    float wy = (q < cntB) ? bf_hi(uB[q]) : 0.f;
    if (q & 1) { aA1.x += vx; aA1.y += vy; aB1.x += wx; aB1.y += wy; }
    else       { aA0.x += vx; aA0.y += vy; aB0.x += wx; aB0.y += wy; }
  }
  const int mx = max(cntA, cntB);
  for (int j = 16; j < mx; j += 8) {
    unsigned tA[8], tB[8];
#pragma unroll
    for (int q = 0; q < 8; ++q) {
      int sA = __shfl(idxA, j + q, 64);
      int sB = __shfl(idxB, j + q, 64);
      tA[q] = ((const unsigned*)(y + (size_t)sA * DIM))[lane];
      tB[q] = ((const unsigned*)(y + (size_t)sB * DIM))[lane];
    }
#pragma unroll
    for (int q = 0; q < 8; ++q) {
      if (j + q < cntA) { aA0.x += bf_lo(tA[q]); aA0.y += bf_hi(tA[q]); }
      if (j + q < cntB) { aB0.x += bf_lo(tB[q]); aB0.y += bf_hi(tB[q]); }
    }
  }

  float2 rA, rB;
  rA.x = fmaxf(aA0.x + aA1.x, 0.f);  rA.y = fmaxf(aA0.y + aA1.y, 0.f);
  rB.x = fmaxf(aB0.x + aB1.x, 0.f);  rB.y = fmaxf(aB0.y + aB1.y, 0.f);

  float sA = waveSum(rA.x * rA.x + rA.y * rA.y);
  float sB = waveSum(rB.x * rB.x + rB.y * rB.y);

  float nA = fmaxf(sqrtf(sA), EPSF);
  float nmA = fminf(nA, MAXNORM);
  float scA = 0.5f * logf((1.0f + nmA) / (1.0f - nmA)) / nA;
  float nB = fmaxf(sqrtf(sB), EPSF);
  float nmB = fminf(nB, MAXNORM);
  float scB = 0.5f * logf((1.0f + nmB) / (1.0f - nmB)) / nB;

  unsigned oA = (unsigned)f2bf(rA.x * scA) | ((unsigned)f2bf(rA.y * scA) << 16);
  unsigned oB = (unsigned)f2bf(rB.x * scB) | ((unsigned)f2bf(rB.y * scB) << 16);
  ((unsigned*)(tout + (size_t)nodeA * DIM))[lane] = oA;
  ((unsigned*)(tout + (size_t)nodeB * DIM))[lane] = oB;
}

// ---------------- transform2 role: ONE 64-node tile (bf16 tangent in) ------------
__device__ __forceinline__ void do_t2_tile(
    const unsigned short* __restrict__ t, const unsigned short* __restrict__ Wb,
    const float* __restrict__ b, unsigned short* __restrict__ y,
    unsigned short* At, int tile)
{
  const int tid = threadIdx.x;
  const int w = tid >> 6;
  const int l = tid & 63;
  const int lr = l & 15;
  const int lg = l >> 4;
  const int base = tile * 64;
  const int row = w * 16 + lr;
  const int node = base + row;

  bf16x8 bf[8][4];
#pragma unroll
  for (int n = 0; n < 8; ++n)
#pragma unroll
    for (int kc = 0; kc < 4; ++kc)
      bf[n][kc] = *(const bf16x8*)(Wb + (n * 16 + lr) * DIM + kc * 32 + lg * 8);

  float bias[8];
#pragma unroll
  for (int n = 0; n < 8; ++n) bias[n] = b[n * 16 + lr];

#pragma unroll
  for (int s = 0; s < 4; ++s) {
    bf16x8 frag;
    if (node < N_NODES)
      frag = *(const bf16x8*)(t + (size_t)node * DIM + lg * 32 + s * 8);
    else
      frag = bf16x8{0, 0, 0, 0, 0, 0, 0, 0};
    int byte = row * 256 + lg * 64 + s * 16;
    byte ^= (row & 7) << 4;
    *(bf16x8*)((char*)At + byte) = frag;
  }
  __syncthreads();

  f32x4 acc[8];
#pragma unroll
  for (int n = 0; n < 8; ++n) {
    acc[n][0] = bias[n]; acc[n][1] = bias[n]; acc[n][2] = bias[n]; acc[n][3] = bias[n];
  }
#pragma unroll
  for (int kc = 0; kc < 4; ++kc) {
    int byte = row * 256 + kc * 64 + lg * 16;
    byte ^= (row & 7) << 4;
    bf16x8 af = *(const bf16x8*)((const char*)At + byte);
#pragma unroll
    for (int n = 0; n < 8; ++n)
      acc[n] = __builtin_amdgcn_mfma_f32_16x16x32_bf16(af, bf[n][kc], acc[n], 0, 0, 0);
  }

  float rs[4];
#pragma unroll
  for (int j = 0; j < 4; ++j) {
    float s2 = 0.f;
#pragma unroll
    for (int n = 0; n < 8; ++n) s2 += acc[n][j] * acc[n][j];
    s2 += __shfl_xor(s2, 1, 64);
    s2 += __shfl_xor(s2, 2, 64);
    s2 += __shfl_xor(s2, 4, 64);
    s2 += __shfl_xor(s2, 8, 64);
    float n2 = sqrtf(s2);
    float n2c = fmaxf(n2, EPSF);
    rs[j] = tanhf(n2c) / n2c;
  }
#pragma unroll
  for (int j = 0; j < 4; ++j) {
    int nrow = base + w * 16 + lg * 4 + j;
    if (nrow < N_NODES) {
      unsigned short* yr = y + (size_t)nrow * DIM + lr;
#pragma unroll
      for (int n = 0; n < 8; ++n) yr[n * 16] = f2bf(acc[n][j] * rs[j]);
    }
  }
}

// ---------------- head role: ONE 64-node tile ------------------------------------
__device__ __forceinline__ void do_head_tile(
    const unsigned short* __restrict__ t2, const float* __restrict__ Wc,
    const float* __restrict__ bc, float* __restrict__ out, int tile)
{
  const int base = tile * 64;
  const int w = (int)threadIdx.x >> 6;
  const int l = threadIdx.x & 63;
  const int lr = l & 15;
  const int lg = l >> 4;

  bf16x8 bw[4];
#pragma unroll
  for (int kc = 0; kc < 4; ++kc) {
    unsigned short tmp[8];
    if (lr < NCLS) {
      const float* wr = Wc + (size_t)lr * DIM + kc * 32 + lg * 8;
#pragma unroll
      for (int e = 0; e < 8; ++e) tmp[e] = f2bf(wr[e]);
    } else {
#pragma unroll
      for (int e = 0; e < 8; ++e) tmp[e] = 0;
    }
    bw[kc] = *(const bf16x8*)tmp;
  }
  const float bias = (lr < NCLS) ? bc[lr] : 0.f;

  const int arow = base + w * 16 + lr;
  f32x4 acc;
  acc[0] = bias; acc[1] = bias; acc[2] = bias; acc[3] = bias;
#pragma unroll
  for (int kc = 0; kc < 4; ++kc) {
    bf16x8 af;
    if (arow < N_NODES)
      af = *(const bf16x8*)(t2 + (size_t)arow * DIM + kc * 32 + lg * 8);
    else
      af = bf16x8{0, 0, 0, 0, 0, 0, 0, 0};
    acc = __builtin_amdgcn_mfma_f32_16x16x32_bf16(af, bw[kc], acc, 0, 0, 0);
  }

  if (lr < NCLS) {
#pragma unroll
    for (int j = 0; j < 4; ++j) {
      int nrow = base + w * 16 + lg * 4 + j;
      if (nrow < N_NODES) out[(size_t)nrow * NCLS + lr] = acc[j];
    }
  }
}

// ======================= back-half pipeline kernels =======================

// gather over node range [nodeLo + 8*bid, +8)
__global__ __launch_bounds__(256) void gather_range(
    const unsigned short* __restrict__ y, const int* __restrict__ cursor,
    const unsigned short* __restrict__ ell, unsigned short* __restrict__ tout,
    int nodeLo)
{
  do_gather2(y, cursor, ell, tout, blockIdx.x, nodeLo);
}

// g1B (nodes >= SPLIT, reads ybuf, writes tbuf[>=S]) || t2A (tiles < STILE,
// reads tbuf[<S], writes y2buf[<S]) — all regions disjoint.
__global__ __launch_bounds__(256, 2) void g1B_t2A(
    const unsigned short* __restrict__ ybuf, const int* __restrict__ cursor,
    const unsigned short* __restrict__ ell, unsigned short* __restrict__ tbuf,
    const unsigned short* __restrict__ W2b, const float* __restrict__ b2,
    unsigned short* __restrict__ y2buf)
{
  __shared__ __align__(16) unsigned short At[64 * DIM];
  if (blockIdx.x < GB_BLKS) {
    do_gather2(ybuf, cursor, ell, tbuf, blockIdx.x, SPLIT);
  } else {
    do_t2_tile(tbuf, W2b, b2, y2buf, At, blockIdx.x - GB_BLKS);
  }
}

// t2B: tiles [STILE, NTILE)
__global__ __launch_bounds__(256, 2) void t2B_kernel(
    const unsigned short* __restrict__ tbuf, const unsigned short* __restrict__ W2b,
    const float* __restrict__ b2, unsigned short* __restrict__ y2buf)
{
  __shared__ __align__(16) unsigned short At[64 * DIM];
  do_t2_tile(tbuf, W2b, b2, y2buf, At, STILE + blockIdx.x);
}

// g2B (nodes >= SPLIT, reads y2buf, writes tbuf[>=S]) || headA (tiles < STILE,
// reads tbuf[<S] written by g2A, writes out) — disjoint.
__global__ __launch_bounds__(256) void g2B_headA(
    const unsigned short* __restrict__ y2buf, const int* __restrict__ cursor,
    const unsigned short* __restrict__ ell, unsigned short* __restrict__ tbuf,
    const float* __restrict__ Wc, const float* __restrict__ bc,
    float* __restrict__ out)
{
  if (blockIdx.x < GB_BLKS) {
    do_gather2(y2buf, cursor, ell, tbuf, blockIdx.x, SPLIT);
  } else {
    do_head_tile(tbuf, Wc, bc, out, blockIdx.x - GB_BLKS);
  }
}

// headB: tiles [STILE, NTILE)
__global__ __launch_bounds__(256) void headB_kernel(
    const unsigned short* __restrict__ tbuf, const float* __restrict__ Wc,
    const float* __restrict__ bc, float* __restrict__ out)
{
  do_head_tile(tbuf, Wc, bc, out, STILE + blockIdx.x);
}

extern "C" void kernel_launch(void* const* d_in, const int* in_sizes, int n_in,
                              void* d_out, int out_size, void* d_ws, size_t ws_size,
                              hipStream_t stream)
{
  const int* edge = (const int*)d_in[0];
  const int* src = edge;            // edge_index[0]
  const int* dst = edge + N_EDGES;  // edge_index[1]
  const float* x  = (const float*)d_in[1];
  const float* W1 = (const float*)d_in[2];
  const float* b1 = (const float*)d_in[3];
  const float* W2 = (const float*)d_in[4];
  const float* b2 = (const float*)d_in[5];
  const float* Wc = (const float*)d_in[6];
  const float* bc = (const float*)d_in[7];
  float* out = (float*)d_out;

  unsigned short* ybuf  = (unsigned short*)d_ws;           // bf16 y1 [N, D]
  unsigned short* tbuf  = ybuf + (size_t)N_NODES * DIM;    // bf16 tangent [N, D]
  unsigned short* y2buf = tbuf + (size_t)N_NODES * DIM;    // bf16 y2 [N, D]
  unsigned short* W1b = y2buf + (size_t)N_NODES * DIM;
  unsigned short* W2b = W1b + DIM * DIM;
  unsigned short* ell = W2b + DIM * DIM;                   // N_NODES * ELLW (ushort)
  int* cursor = (int*)(ell + (size_t)N_NODES * ELLW);      // N_NODES * CURSTRIDE

  // K1: zero cursors + W->bf16
  init_kernel<<<(N_NODES + 255) / 256, 256, 0, stream>>>(cursor, W1, W2, W1b, W2b);

  // K2: ELL fill || layer-1 transform -> ybuf
  fill_transform<<<FILLB + XFB, 256, 0, stream>>>(src, dst, cursor, ell, x, W1b, b1, ybuf);

  // K3: gather1 nodes [0, SPLIT): ybuf -> tbuf[<S]
  gather_range<<<GA_BLKS, 256, 0, stream>>>(ybuf, cursor, ell, tbuf, 0);

  // K4: gather1 nodes [SPLIT, N) || transform2 tiles [0, STILE)
  g1B_t2A<<<GB_BLKS + STILE, 256, 0, stream>>>(ybuf, cursor, ell, tbuf, W2b, b2, y2buf);

  // K5: transform2 tiles [STILE, NTILE)
  t2B_kernel<<<NTILE - STILE, 256, 0, stream>>>(tbuf, W2b, b2, y2buf);

  // K6: gather2 nodes [0, SPLIT): y2buf -> tbuf[<S]
  gather_range<<<GA_BLKS, 256, 0, stream>>>(y2buf, cursor, ell, tbuf, 0);

  // K7: gather2 nodes [SPLIT, N) || head tiles [0, STILE)
  g2B_headA<<<GB_BLKS + STILE, 256, 0, stream>>>(y2buf, cursor, ell, tbuf, Wc, bc, out);

  // K8: head tiles [STILE, NTILE)
  headB_kernel<<<NTILE - STILE, 256, 0, stream>>>(tbuf, Wc, bc, out);
}

// Round 22
// 127.229 us; speedup vs baseline: 1.1136x; 1.1136x over previous
//
#include <hip/hip_runtime.h>

#define N_NODES 50000
#define N_EDGES 600000
#define DIM 128
#define NCLS 10
#define ELLW 64                 // max degree (mean 12; P(>64) astronomically small)
#define CURSTRIDE 16            // one cursor per 64B line
#define EPSF 1e-15f
#define MAXNORM 0.99999f        // 1 - 1e-5
#define NTILE ((N_NODES + 63) / 64)   // 782
#define FILLB 586               // ceil(600000/(256*4))
#define XFB 512                 // persistent transform blocks

typedef __attribute__((ext_vector_type(8))) short bf16x8;
typedef __attribute__((ext_vector_type(4))) float f32x4;

__device__ inline float waveSum(float v) {
#pragma unroll
  for (int o = 1; o < 64; o <<= 1) v += __shfl_xor(v, o, 64);
  return v;
}

__device__ inline unsigned short f2bf(float f) {
  union { float f; unsigned u; } c; c.f = f;
  return (unsigned short)((c.u + 0x7FFFu + ((c.u >> 16) & 1u)) >> 16);
}
__device__ inline float bf_lo(unsigned u) {
  union { unsigned u; float f; } c; c.u = u << 16; return c.f;
}
__device__ inline float bf_hi(unsigned u) {
  union { unsigned u; float f; } c; c.u = u & 0xFFFF0000u; return c.f;
}

// ---------------- init: zero cursors + convert W1/W2 to bf16 ----------------
__global__ __launch_bounds__(256) void init_kernel(
    int* __restrict__ cursor, const float* __restrict__ W1, const float* __restrict__ W2,
    unsigned short* __restrict__ W1b, unsigned short* __restrict__ W2b)
{
  int i = blockIdx.x * 256 + threadIdx.x;
  if (i < N_NODES) cursor[i * CURSTRIDE] = 0;
  if (i < DIM * DIM) {
    W1b[i] = f2bf(W1[i]);
    W2b[i] = f2bf(W2[i]);
  }
}

// ---------------- fused: ELL fill + layer-1 transform (proven 47us) --------------
__global__ __launch_bounds__(256, 2) void fill_transform(
    const int* __restrict__ src, const int* __restrict__ dst,
    int* __restrict__ cursor, unsigned short* __restrict__ ell,
    const float* __restrict__ x, const unsigned short* __restrict__ Wb,
    const float* __restrict__ b, unsigned short* __restrict__ y)
{
  __shared__ __align__(16) unsigned short At[64 * DIM];

  if (blockIdx.x < FILLB) {
    const int nthr = FILLB * 256;
    const int e = blockIdx.x * 256 + threadIdx.x;
    const int e0 = e, e1 = e + nthr, e2 = e + 2 * nthr, e3 = e + 3 * nthr;
    int d0, d1, d2, d3, s0, s1, s2, s3;
    if (e0 < N_EDGES) { d0 = dst[e0]; s0 = src[e0]; }
    if (e1 < N_EDGES) { d1 = dst[e1]; s1 = src[e1]; }
    if (e2 < N_EDGES) { d2 = dst[e2]; s2 = src[e2]; }
    if (e3 < N_EDGES) { d3 = dst[e3]; s3 = src[e3]; }
    int p0, p1, p2, p3;
    if (e0 < N_EDGES) p0 = atomicAdd(&cursor[d0 * CURSTRIDE], 1);
    if (e1 < N_EDGES) p1 = atomicAdd(&cursor[d1 * CURSTRIDE], 1);
    if (e2 < N_EDGES) p2 = atomicAdd(&cursor[d2 * CURSTRIDE], 1);
    if (e3 < N_EDGES) p3 = atomicAdd(&cursor[d3 * CURSTRIDE], 1);
    if (e0 < N_EDGES) ell[(size_t)d0 * ELLW + p0] = (unsigned short)s0;
    if (e1 < N_EDGES) ell[(size_t)d1 * ELLW + p1] = (unsigned short)s1;
    if (e2 < N_EDGES) ell[(size_t)d2 * ELLW + p2] = (unsigned short)s2;
    if (e3 < N_EDGES) ell[(size_t)d3 * ELLW + p3] = (unsigned short)s3;
    return;
  }

  // ---------------- transform path (layer 1: f32 manifold in) ----------------
  const int tid = threadIdx.x;
  const int w = tid >> 6;
  const int l = tid & 63;
  const int lr = l & 15;
  const int lg = l >> 4;

  bf16x8 bf[8][4];
#pragma unroll
  for (int n = 0; n < 8; ++n)
#pragma unroll
    for (int kc = 0; kc < 4; ++kc)
      bf[n][kc] = *(const bf16x8*)(Wb + (n * 16 + lr) * DIM + kc * 32 + lg * 8);

  float bias[8];
#pragma unroll
  for (int n = 0; n < 8; ++n) bias[n] = b[n * 16 + lr];

  const int row = w * 16 + lr;

  for (int tile = blockIdx.x - FILLB; tile < NTILE; tile += XFB) {
    const int base = tile * 64;
    const int node = base + row;
    __syncthreads();

    float v[32];
    if (node < N_NODES) {
      const float4* xr = (const float4*)(x + (size_t)node * DIM + lg * 32);
#pragma unroll
      for (int q = 0; q < 8; ++q) {
        float4 f = xr[q];
        v[q * 4 + 0] = f.x; v[q * 4 + 1] = f.y; v[q * 4 + 2] = f.z; v[q * 4 + 3] = f.w;
      }
    } else {
#pragma unroll
      for (int q = 0; q < 32; ++q) v[q] = 0.f;
    }
    float sq = 0.f;
#pragma unroll
    for (int q = 0; q < 32; ++q) sq += v[q] * v[q];
    sq += __shfl_xor(sq, 16, 64);
    sq += __shfl_xor(sq, 32, 64);
    float n1 = sqrtf(sq);
    float nc = fmaxf(n1, EPSF);
    float nm = fminf(nc, MAXNORM);
    float scale = 0.5f * logf((1.f + nm) / (1.f - nm)) / nc;
#pragma unroll
    for (int s = 0; s < 4; ++s) {
      unsigned short tmp[8];
#pragma unroll
      for (int e = 0; e < 8; ++e) tmp[e] = f2bf(v[s * 8 + e] * scale);
      int byte = row * 256 + lg * 64 + s * 16;
      byte ^= (row & 7) << 4;
      *(bf16x8*)((char*)At + byte) = *(const bf16x8*)tmp;
    }
    __syncthreads();

    f32x4 acc[8];
#pragma unroll
    for (int n = 0; n < 8; ++n) {
      acc[n][0] = bias[n]; acc[n][1] = bias[n]; acc[n][2] = bias[n]; acc[n][3] = bias[n];
    }
#pragma unroll
    for (int kc = 0; kc < 4; ++kc) {
      int byte = row * 256 + kc * 64 + lg * 16;
      byte ^= (row & 7) << 4;
      bf16x8 af = *(const bf16x8*)((const char*)At + byte);
#pragma unroll
      for (int n = 0; n < 8; ++n)
        acc[n] = __builtin_amdgcn_mfma_f32_16x16x32_bf16(af, bf[n][kc], acc[n], 0, 0, 0);
    }

    float rs[4];
#pragma unroll
    for (int j = 0; j < 4; ++j) {
      float s2 = 0.f;
#pragma unroll
      for (int n = 0; n < 8; ++n) s2 += acc[n][j] * acc[n][j];
      s2 += __shfl_xor(s2, 1, 64);
      s2 += __shfl_xor(s2, 2, 64);
      s2 += __shfl_xor(s2, 4, 64);
      s2 += __shfl_xor(s2, 8, 64);
      float n2 = sqrtf(s2);
      float n2c = fmaxf(n2, EPSF);
      rs[j] = tanhf(n2c) / n2c;
    }
#pragma unroll
    for (int j = 0; j < 4; ++j) {
      int nrow = base + w * 16 + lg * 4 + j;
      if (nrow < N_NODES) {
        unsigned short* yr = y + (size_t)nrow * DIM + lr;
#pragma unroll
        for (int n = 0; n < 8; ++n) yr[n * 16] = f2bf(acc[n][j] * rs[j]);
      }
    }
  }
}

// ---------------- gather + relu + logmap0 -> bf16 tangent ------------------------
// 2 nodes per wave (32 outstanding row loads); unconditional index load breaks
// the cnt->index serial chain. 8 nodes/block, 6250 blocks.
__global__ __launch_bounds__(256) void gatherT_kernel(
    const unsigned short* __restrict__ y, const int* __restrict__ cursor,
    const unsigned short* __restrict__ ell, unsigned short* __restrict__ tout)
{
  const int wave = threadIdx.x >> 6;
  const int lane = threadIdx.x & 63;
  const int nodeA = blockIdx.x * 8 + wave * 2;
  const int nodeB = nodeA + 1;   // N_NODES = 50000 = 6250*8, always in range

  const int cntA = cursor[nodeA * CURSTRIDE];
  const int cntB = cursor[nodeB * CURSTRIDE];
  const int idxA = (int)ell[(size_t)nodeA * ELLW + lane];  // unconditional 128B load
  const int idxB = (int)ell[(size_t)nodeB * ELLW + lane];

  float2 aA0 = {0.f, 0.f}, aA1 = {0.f, 0.f};
  float2 aB0 = {0.f, 0.f}, aB1 = {0.f, 0.f};

  // 16-deep predicated batches for both nodes: 32 loads in flight.
  unsigned uA[16], uB[16];
#pragma unroll
  for (int q = 0; q < 16; ++q) {
    int sA = __shfl(idxA, q, 64);
    int sB = __shfl(idxB, q, 64);
    uA[q] = ((const unsigned*)(y + (size_t)sA * DIM))[lane];
    uB[q] = ((const unsigned*)(y + (size_t)sB * DIM))[lane];
  }
#pragma unroll
  for (int q = 0; q < 16; ++q) {
    float vx = (q < cntA) ? bf_lo(uA[q]) : 0.f;
    float vy = (q < cntA) ? bf_hi(uA[q]) : 0.f;
    float wx = (q < cntB) ? bf_lo(uB[q]) : 0.f;
    float wy = (q < cntB) ? bf_hi(uB[q]) : 0.f;
    if (q & 1) { aA1.x += vx; aA1.y += vy; aB1.x += wx; aB1.y += wy; }
    else       { aA0.x += vx; aA0.y += vy; aB0.x += wx; aB0.y += wy; }
  }
  // --- rare tail: cnt > 16 ---
  const int mx = max(cntA, cntB);
  for (int j = 16; j < mx; j += 8) {
    unsigned tA[8], tB[8];
#pragma unroll
    for (int q = 0; q < 8; ++q) {
      int sA = __shfl(idxA, j + q, 64);
      int sB = __shfl(idxB, j + q, 64);
      tA[q] = ((const unsigned*)(y + (size_t)sA * DIM))[lane];
      tB[q] = ((const unsigned*)(y + (size_t)sB * DIM))[lane];
    }
#pragma unroll
    for (int q = 0; q < 8; ++q) {
      if (j + q < cntA) { aA0.x += bf_lo(tA[q]); aA0.y += bf_hi(tA[q]); }
      if (j + q < cntB) { aB0.x += bf_lo(tB[q]); aB0.y += bf_hi(tB[q]); }
    }
  }

  float2 rA, rB;
  rA.x = fmaxf(aA0.x + aA1.x, 0.f);  rA.y = fmaxf(aA0.y + aA1.y, 0.f);
  rB.x = fmaxf(aB0.x + aB1.x, 0.f);  rB.y = fmaxf(aB0.y + aB1.y, 0.f);

  float sA = waveSum(rA.x * rA.x + rA.y * rA.y);
  float sB = waveSum(rB.x * rB.x + rB.y * rB.y);

  float nA = fmaxf(sqrtf(sA), EPSF);
  float nmA = fminf(nA, MAXNORM);
  float scA = 0.5f * logf((1.0f + nmA) / (1.0f - nmA)) / nA;
  float nB = fmaxf(sqrtf(sB), EPSF);
  float nmB = fminf(nB, MAXNORM);
  float scB = 0.5f * logf((1.0f + nmB) / (1.0f - nmB)) / nB;

  unsigned oA = (unsigned)f2bf(rA.x * scA) | ((unsigned)f2bf(rA.y * scA) << 16);
  unsigned oB = (unsigned)f2bf(rB.x * scB) | ((unsigned)f2bf(rB.y * scB) << 16);
  ((unsigned*)(tout + (size_t)nodeA * DIM))[lane] = oA;
  ((unsigned*)(tout + (size_t)nodeB * DIM))[lane] = oB;
}

// ---------------- layer-2 transform: bf16 tangent in -> (W t + b) -> expmap0 ------
__global__ __launch_bounds__(256, 2) void transform2_mfma(
    const unsigned short* __restrict__ t, const unsigned short* __restrict__ Wb,
    const float* __restrict__ b, unsigned short* __restrict__ y)
{
  const int tid = threadIdx.x;
  const int w = tid >> 6;
  const int l = tid & 63;
  const int lr = l & 15;
  const int lg = l >> 4;

  __shared__ __align__(16) unsigned short At[64 * DIM];

  bf16x8 bf[8][4];
#pragma unroll
  for (int n = 0; n < 8; ++n)
#pragma unroll
    for (int kc = 0; kc < 4; ++kc)
      bf[n][kc] = *(const bf16x8*)(Wb + (n * 16 + lr) * DIM + kc * 32 + lg * 8);

  float bias[8];
#pragma unroll
  for (int n = 0; n < 8; ++n) bias[n] = b[n * 16 + lr];

  const int row = w * 16 + lr;

  for (int tile = blockIdx.x; tile < NTILE; tile += gridDim.x) {
    const int base = tile * 64;
    const int node = base + row;
    __syncthreads();

#pragma unroll
    for (int s = 0; s < 4; ++s) {
      bf16x8 frag;
      if (node < N_NODES)
        frag = *(const bf16x8*)(t + (size_t)node * DIM + lg * 32 + s * 8);
      else
        frag = bf16x8{0, 0, 0, 0, 0, 0, 0, 0};
      int byte = row * 256 + lg * 64 + s * 16;
      byte ^= (row & 7) << 4;
      *(bf16x8*)((char*)At + byte) = frag;
    }
    __syncthreads();

    f32x4 acc[8];
#pragma unroll
    for (int n = 0; n < 8; ++n) {
      acc[n][0] = bias[n]; acc[n][1] = bias[n]; acc[n][2] = bias[n]; acc[n][3] = bias[n];
    }
#pragma unroll
    for (int kc = 0; kc < 4; ++kc) {
      int byte = row * 256 + kc * 64 + lg * 16;
      byte ^= (row & 7) << 4;
      bf16x8 af = *(const bf16x8*)((const char*)At + byte);
#pragma unroll
      for (int n = 0; n < 8; ++n)
        acc[n] = __builtin_amdgcn_mfma_f32_16x16x32_bf16(af, bf[n][kc], acc[n], 0, 0, 0);
    }

    float rs[4];
#pragma unroll
    for (int j = 0; j < 4; ++j) {
      float s2 = 0.f;
#pragma unroll
      for (int n = 0; n < 8; ++n) s2 += acc[n][j] * acc[n][j];
      s2 += __shfl_xor(s2, 1, 64);
      s2 += __shfl_xor(s2, 2, 64);
      s2 += __shfl_xor(s2, 4, 64);
      s2 += __shfl_xor(s2, 8, 64);
      float n2 = sqrtf(s2);
      float n2c = fmaxf(n2, EPSF);
      rs[j] = tanhf(n2c) / n2c;
    }
#pragma unroll
    for (int j = 0; j < 4; ++j) {
      int nrow = base + w * 16 + lg * 4 + j;
      if (nrow < N_NODES) {
        unsigned short* yr = y + (size_t)nrow * DIM + lr;
#pragma unroll
        for (int n = 0; n < 8; ++n) yr[n * 16] = f2bf(acc[n][j] * rs[j]);
      }
    }
  }
}

// ---------------- classifier head: out = t2 @ Wc^T + bc via MFMA ----------------
__global__ __launch_bounds__(256) void head_mfma(
    const unsigned short* __restrict__ t2, const float* __restrict__ Wc,
    const float* __restrict__ bc, float* __restrict__ out)
{
  const int base = blockIdx.x * 64;
  const int w = threadIdx.x >> 6;
  const int l = threadIdx.x & 63;
  const int lr = l & 15;
  const int lg = l >> 4;

  bf16x8 bw[4];
#pragma unroll
  for (int kc = 0; kc < 4; ++kc) {
    unsigned short tmp[8];
    if (lr < NCLS) {
      const float* wr = Wc + (size_t)lr * DIM + kc * 32 + lg * 8;
#pragma unroll
      for (int e = 0; e < 8; ++e) tmp[e] = f2bf(wr[e]);
    } else {
#pragma unroll
      for (int e = 0; e < 8; ++e) tmp[e] = 0;
    }
    bw[kc] = *(const bf16x8*)tmp;
  }
  const float bias = (lr < NCLS) ? bc[lr] : 0.f;

  const int arow = base + w * 16 + lr;
  f32x4 acc;
  acc[0] = bias; acc[1] = bias; acc[2] = bias; acc[3] = bias;
#pragma unroll
  for (int kc = 0; kc < 4; ++kc) {
    bf16x8 af;
    if (arow < N_NODES)
      af = *(const bf16x8*)(t2 + (size_t)arow * DIM + kc * 32 + lg * 8);
    else
      af = bf16x8{0, 0, 0, 0, 0, 0, 0, 0};
    acc = __builtin_amdgcn_mfma_f32_16x16x32_bf16(af, bw[kc], acc, 0, 0, 0);
  }

  if (lr < NCLS) {
#pragma unroll
    for (int j = 0; j < 4; ++j) {
      int nrow = base + w * 16 + lg * 4 + j;
      if (nrow < N_NODES) out[(size_t)nrow * NCLS + lr] = acc[j];
    }
  }
}

extern "C" void kernel_launch(void* const* d_in, const int* in_sizes, int n_in,
                              void* d_out, int out_size, void* d_ws, size_t ws_size,
                              hipStream_t stream)
{
  const int* edge = (const int*)d_in[0];
  const int* src = edge;            // edge_index[0]
  const int* dst = edge + N_EDGES;  // edge_index[1]
  const float* x  = (const float*)d_in[1];
  const float* W1 = (const float*)d_in[2];
  const float* b1 = (const float*)d_in[3];
  const float* W2 = (const float*)d_in[4];
  const float* b2 = (const float*)d_in[5];
  const float* Wc = (const float*)d_in[6];
  const float* bc = (const float*)d_in[7];
  float* out = (float*)d_out;

  unsigned short* ybuf = (unsigned short*)d_ws;          // bf16 y [N, D]
  unsigned short* tbuf = ybuf + (size_t)N_NODES * DIM;   // bf16 tangent [N, D]
  unsigned short* W1b = tbuf + (size_t)N_NODES * DIM;
  unsigned short* W2b = W1b + DIM * DIM;
  unsigned short* ell = W2b + DIM * DIM;                 // N_NODES * ELLW (ushort)
  int* cursor = (int*)(ell + (size_t)N_NODES * ELLW);    // N_NODES * CURSTRIDE

  // --- init (zero cursors) + W->bf16 ---
  init_kernel<<<(N_NODES + 255) / 256, 256, 0, stream>>>(cursor, W1, W2, W1b, W2b);

  // --- ELL fill || layer-1 transform -> ybuf ---
  fill_transform<<<FILLB + XFB, 256, 0, stream>>>(src, dst, cursor, ell, x, W1b, b1, ybuf);

  // --- gather + relu + logmap -> tbuf (2 nodes/wave) ---
  gatherT_kernel<<<N_NODES / 8, 256, 0, stream>>>(ybuf, cursor, ell, tbuf);

  // --- Layer 2: tbuf (bf16 tangent) -> ybuf ---
  transform2_mfma<<<512, 256, 0, stream>>>(tbuf, W2b, b2, ybuf);

  // --- gather + relu + logmap -> tbuf ---
  gatherT_kernel<<<N_NODES / 8, 256, 0, stream>>>(ybuf, cursor, ell, tbuf);

  // --- classifier head ---
  head_mfma<<<NTILE, 256, 0, stream>>>(tbuf, Wc, bc, out);
}